// Round 5
// baseline (256.706 us; speedup 1.0000x reference)
//
#include <hip/hip_runtime.h>
#include <math.h>

#define BB    32
#define TENC  1024
#define TDEC  512
#define DDIM  512
#define NST   512

typedef __bf16 bf16_t;
typedef __bf16 bf16x8 __attribute__((ext_vector_type(8)));
typedef __bf16 bf16x4 __attribute__((ext_vector_type(4)));
typedef float  f32x4  __attribute__((ext_vector_type(4)));

#define GLOAD_LDS16(gp, lp) __builtin_amdgcn_global_load_lds( \
    (const __attribute__((address_space(1))) unsigned int*)(const void*)(gp), \
    (__attribute__((address_space(3))) unsigned int*)(lp), 16, 0, 0)

static __device__ __forceinline__ f32x4 MFMA16(bf16x8 a, bf16x8 b, f32x4 c) {
    return __builtin_amdgcn_mfma_f32_16x16x32_bf16(a, b, c, 0, 0, 0);
}

// ---------------------------------------------------------------------------
// Split f32 -> bf16 hi/lo
__global__ __launch_bounds__(256)
void split_f32_bf16(const float* __restrict__ x, bf16_t* __restrict__ hi,
                    bf16_t* __restrict__ lo, long n4)
{
    long i = (long)blockIdx.x * 256 + threadIdx.x;
    if (i >= n4) return;
    float4 v = *(const float4*)&x[i * 4];
    float f[4] = {v.x, v.y, v.z, v.w};
    bf16x4 h, l;
#pragma unroll
    for (int e = 0; e < 4; ++e) {
        bf16_t hh = (bf16_t)f[e];
        h[e] = hh;
        l[e] = (bf16_t)(f[e] - (float)hh);
    }
    *(bf16x4*)&hi[i * 4] = h;
    *(bf16x4*)&lo[i * 4] = l;
}

// ---------------------------------------------------------------------------
// Tiled transpose: out[c][r] = bf16(in[r][c])
template<typename TIN>
__global__ __launch_bounds__(256)
void transpose_to_bf16(const TIN* __restrict__ in, bf16_t* __restrict__ out,
                       int R, int C, long sIn, long sOut)
{
    __shared__ bf16_t tile[64][65];
    const long b = blockIdx.z;
    in  += b * sIn;
    out += b * sOut;
    const int c0 = blockIdx.x * 64, r0 = blockIdx.y * 64;
    const int t = threadIdx.x;
    const int rr = t >> 4;
    const int cc = (t & 15) * 4;
#pragma unroll
    for (int p = 0; p < 4; ++p) {
        int r = rr + p * 16;
        if constexpr (sizeof(TIN) == 4) {
            float4 v = *(const float4*)&in[(long)(r0 + r) * C + c0 + cc];
            tile[r][cc + 0] = (bf16_t)v.x;
            tile[r][cc + 1] = (bf16_t)v.y;
            tile[r][cc + 2] = (bf16_t)v.z;
            tile[r][cc + 3] = (bf16_t)v.w;
        } else {
            bf16x4 v = *(const bf16x4*)&in[(long)(r0 + r) * C + c0 + cc];
            tile[r][cc + 0] = v[0];
            tile[r][cc + 1] = v[1];
            tile[r][cc + 2] = v[2];
            tile[r][cc + 3] = v[3];
        }
    }
    __syncthreads();
    const int dr = t >> 2;
    const int tc = (t & 3) * 16;
    bf16_t tmp[16];
#pragma unroll
    for (int e = 0; e < 16; ++e) tmp[e] = tile[tc + e][dr];
    *(bf16x8*)&out[(long)(c0 + dr) * R + r0 + tc]     = *(bf16x8*)&tmp[0];
    *(bf16x8*)&out[(long)(c0 + dr) * R + r0 + tc + 8] = *(bf16x8*)&tmp[8];
}

// ---------------------------------------------------------------------------
// Split GEMM, occupancy-first variant.
// C[M,N] = (Ahi+Alo)[M,K] @ ((Bhi+Blo)[N,K])^T, dropping lo*lo.
// BM=128, BN=128, BK=32, 4 waves (2x2, wave-tile 64x64).
// A (L2/L3-resident) loaded DIRECT global->register (no LDS).
// B staged hi+lo in 16KB LDS buffers, double-buffered (32KB total)
//   -> 3 blocks/CU at <=170 VGPR (12 waves/CU vs 8 before).
// Counted vmcnt(4); raw barriers; setprio around MFMA cluster; XCD swizzle.
// EPI: 0 = f32 out, 1 = split bf16 out (C0=hi,C1=lo).
template<int EPI>
__global__ __launch_bounds__(256, 3)
void gemm_split4(const bf16_t* __restrict__ Ahi, const bf16_t* __restrict__ Alo,
                 const bf16_t* __restrict__ Bhi, const bf16_t* __restrict__ Blo,
                 void* __restrict__ C0, void* __restrict__ C1,
                 int M, int N, int K, long sA, long sB, long sC)
{
    // per buffer (bf16 elems): Bh [0,4096), Bl [4096,8192)
    __shared__ bf16_t lds[2][8192];

    const int tid  = threadIdx.x;
    const int wave = tid >> 6;
    const int lane = tid & 63;

    // T1: bijective XCD swizzle (all grids used are multiples of 8)
    const int gx = gridDim.x, gy = gridDim.y;
    const long nwg = (long)gx * gy * gridDim.z;
    const long f  = ((long)blockIdx.z * gy + blockIdx.y) * gx + blockIdx.x;
    const long f2 = (f & 7) * (nwg >> 3) + (f >> 3);
    const int bx  = (int)(f2 % gx);
    const int by  = (int)((f2 / gx) % gy);
    const long bz = f2 / ((long)gx * gy);

    const bf16_t* Ah = Ahi + bz * sA;
    const bf16_t* Al = Alo + bz * sA;
    const bf16_t* Bh = Bhi + bz * sB;
    const bf16_t* Bl = Blo + bz * sB;

    const int row0 = by * 128;
    const int col0 = bx * 128;
    const int wr = (wave >> 1) * 64;   // wave row offset
    const int wc = (wave & 1) * 64;    // wave col offset

    // B staging: 4 issues/tile, each 256 thr x 16B = 64 rows x 32k.
    // LDS dest linear; global k-slot pre-swizzled (rule #21).
    const int srow  = wave * 16 + (lane >> 2);           // 0..63 within issue
    const int sslot = (lane & 3) ^ ((srow >> 1) & 3);
    const long bOff0 = (long)(col0 + srow) * K + sslot * 8;        // rows 0-63
    const long bOff1 = (long)(col0 + 64 + srow) * K + sslot * 8;   // rows 64-127
    const int ldsW = wave * 512;   // elems, per-issue wave chunk

    // fragment indices
    const int fr = lane & 15;
    const int q  = lane >> 4;          // k-slot 0..3
    int bro[4];
#pragma unroll
    for (int j = 0; j < 4; ++j) {
        const int r = wc + j * 16 + fr;
        bro[j] = r * 32 + ((q ^ ((r >> 1) & 3)) * 8);
    }
    // A direct-load row addresses (global, K-contiguous 16B per lane)
    long aAddr[4];
#pragma unroll
    for (int i = 0; i < 4; ++i)
        aAddr[i] = (long)(row0 + wr + i * 16 + fr) * K + q * 8;

    f32x4 acc[4][4] = {};
    const int NT = K >> 5;

#define ISSUE_B(dst, roff, gptr) GLOAD_LDS16((gptr), &(dst)[(roff) + ldsW])

    // prologue: B(0) -> buf0 (4 issues), A(0) -> regs
    {
        bf16_t* b0 = lds[0];
        ISSUE_B(b0, 0,    Bh + bOff0);
        ISSUE_B(b0, 2048, Bh + bOff1);
        ISSUE_B(b0, 4096, Bl + bOff0);
        ISSUE_B(b0, 6144, Bl + bOff1);
    }
    bf16x8 aH[4], aL[4];
#pragma unroll
    for (int i = 0; i < 4; ++i) {
        aH[i] = *(const bf16x8*)&Ah[aAddr[i]];
        aL[i] = *(const bf16x8*)&Al[aAddr[i]];
    }

    for (int t = 0; t < NT; ++t) {
        bf16_t* cur = lds[t & 1];
        bf16_t* nxt = lds[(t & 1) ^ 1];
        const int ktn = (t + 1) << 5;
        const bool pf = (t + 1 < NT);

        __builtin_amdgcn_sched_barrier(0);
        __builtin_amdgcn_s_barrier();      // all waves done reading nxt (tile t-1)
        if (pf) {
            ISSUE_B(nxt, 0,    Bh + bOff0 + ktn);
            ISSUE_B(nxt, 2048, Bh + bOff1 + ktn);
            ISSUE_B(nxt, 4096, Bl + bOff0 + ktn);
            ISSUE_B(nxt, 6144, Bl + bOff1 + ktn);
            // drains B(t) + a(t); leaves the 4 B(t+1) in flight
            asm volatile("s_waitcnt vmcnt(4)" ::: "memory");
        } else {
            asm volatile("s_waitcnt vmcnt(0)" ::: "memory");
        }
        __builtin_amdgcn_s_barrier();      // B(t) visible to all waves
        __builtin_amdgcn_sched_barrier(0);

        bf16x8 bH[4], bL[4];
#pragma unroll
        for (int j = 0; j < 4; ++j) {
            bH[j] = *(const bf16x8*)&cur[bro[j]];
            bL[j] = *(const bf16x8*)&cur[4096 + bro[j]];
        }

        __builtin_amdgcn_s_setprio(1);
#pragma unroll
        for (int j = 0; j < 4; ++j)
#pragma unroll
            for (int i = 0; i < 4; ++i) {
                acc[i][j] = MFMA16(aH[i], bH[j], acc[i][j]);
                acc[i][j] = MFMA16(aH[i], bL[j], acc[i][j]);
                acc[i][j] = MFMA16(aL[i], bH[j], acc[i][j]);
            }
        __builtin_amdgcn_s_setprio(0);

        if (pf) {   // A(t+1) -> regs (after last use of a(t); latency hides
                    // under next tile's barrier + ds_reads + other blocks)
#pragma unroll
            for (int i = 0; i < 4; ++i) {
                aH[i] = *(const bf16x8*)&Ah[aAddr[i] + ktn];
                aL[i] = *(const bf16x8*)&Al[aAddr[i] + ktn];
            }
        }
    }
#undef ISSUE_B

    // epilogue (C/D layout: col = lane&15, row = (lane>>4)*4 + reg)
    const int frow = q * 4;
#pragma unroll
    for (int i = 0; i < 4; ++i) {
        const int rg = row0 + wr + i * 16 + frow;
#pragma unroll
        for (int j = 0; j < 4; ++j) {
            const int cg = col0 + wc + j * 16 + fr;
            if constexpr (EPI == 0) {
                float* C = (float*)C0 + bz * sC;
#pragma unroll
                for (int r = 0; r < 4; ++r)
                    C[(long)(rg + r) * N + cg] = acc[i][j][r];
            } else {
                bf16_t* Ch = (bf16_t*)C0 + bz * sC;
                bf16_t* Cl = (bf16_t*)C1 + bz * sC;
#pragma unroll
                for (int r = 0; r < 4; ++r) {
                    float v = acc[i][j][r];
                    bf16_t h = (bf16_t)v;
                    Ch[(long)(rg + r) * N + cg] = h;
                    Cl[(long)(rg + r) * N + cg] = (bf16_t)(v - (float)h);
                }
            }
        }
    }
}

// ---------------------------------------------------------------------------
// Plain bf16 MFMA GEMM (m97-style) + T1 XCD swizzle — value chain.
// EPI: 2=bf16 out, 3=f32+bias out
template<int EPI>
__global__ __launch_bounds__(256)
void mfma_gemm(const bf16_t* __restrict__ Ahi, const bf16_t* __restrict__ Bhi,
               const float* __restrict__ bias,
               void* __restrict__ C0,
               int M, int N, int K, long sA, long sB, long sC)
{
    __shared__ bf16_t sAh[128 * 32];
    __shared__ bf16_t sBh[128 * 32];

    const int tid  = threadIdx.x;
    const int wave = tid >> 6;
    const int lane = tid & 63;

    // T1: bijective XCD swizzle (grids are multiples of 8)
    const int gx = gridDim.x, gy = gridDim.y;
    const long nwg = (long)gx * gy * gridDim.z;
    const long f  = ((long)blockIdx.z * gy + blockIdx.y) * gx + blockIdx.x;
    const long f2 = (f & 7) * (nwg >> 3) + (f >> 3);
    const int bx  = (int)(f2 % gx);
    const int by  = (int)((f2 / gx) % gy);
    const long bz = f2 / ((long)gx * gy);

    const bf16_t* Ah = Ahi + bz * sA;
    const bf16_t* Bh = Bhi + bz * sB;

    const int row0 = by * 128;
    const int col0 = bx * 128;
    const int wr = (wave >> 1) * 64;
    const int wc = (wave & 1) * 64;

    f32x4 acc[4][4] = {};

    const int ldrow = lane >> 2;
    const int ldcol = (lane & 3) * 8;
    const int hgrp  = (lane >> 4) * 8;
    const int fr    = lane & 15;

    for (int kt = 0; kt < K; kt += 32) {
        __syncthreads();
#pragma unroll
        for (int c = 0; c < 2; ++c) {
            const int chunk = wave * 2 + c;
            const int r = chunk * 16 + ldrow;
            GLOAD_LDS16(Ah + (long)(row0 + r) * K + kt + ldcol, &sAh[chunk * 512]);
            GLOAD_LDS16(Bh + (long)(col0 + r) * K + kt + ldcol, &sBh[chunk * 512]);
        }
        __syncthreads();

        bf16x8 aH[4], bH[4];
#pragma unroll
        for (int i = 0; i < 4; ++i)
            aH[i] = *(const bf16x8*)&sAh[(wr + i * 16 + fr) * 32 + hgrp];
#pragma unroll
        for (int j = 0; j < 4; ++j)
            bH[j] = *(const bf16x8*)&sBh[(wc + j * 16 + fr) * 32 + hgrp];
#pragma unroll
        for (int i = 0; i < 4; ++i)
#pragma unroll
            for (int j = 0; j < 4; ++j)
                acc[i][j] = MFMA16(aH[i], bH[j], acc[i][j]);
    }

    const int frow = (lane >> 4) * 4;
#pragma unroll
    for (int i = 0; i < 4; ++i) {
        const int rg = row0 + wr + i * 16 + frow;
#pragma unroll
        for (int j = 0; j < 4; ++j) {
            const int cg = col0 + wc + j * 16 + fr;
            if constexpr (EPI == 3) {
                float* C = (float*)C0 + bz * sC;
                const float badd = bias[cg];
#pragma unroll
                for (int r = 0; r < 4; ++r)
                    C[(long)(rg + r) * N + cg] = acc[i][j][r] + badd;
            } else {
                bf16_t* Ch = (bf16_t*)C0 + bz * sC;
#pragma unroll
                for (int r = 0; r < 4; ++r)
                    Ch[(long)(rg + r) * N + cg] = (bf16_t)acc[i][j][r];
            }
        }
    }
}

// ---------------------------------------------------------------------------
// Row softmax over length-1024 rows, in place (f32) + bf16 copy.
__global__ __launch_bounds__(256)
void softmax_rows(float* __restrict__ S, bf16_t* __restrict__ Sb)
{
    const long row = (long)blockIdx.x * 4 + (threadIdx.x >> 6);
    const int lane = threadIdx.x & 63;
    float* p = S + row * (long)TENC;

    float4 v[4];
    float m = -INFINITY;
#pragma unroll
    for (int i = 0; i < 4; ++i) {
        v[i] = *(const float4*)&p[i * 256 + lane * 4];
        m = fmaxf(fmaxf(fmaxf(v[i].x, v[i].y), fmaxf(v[i].z, v[i].w)), m);
    }
#pragma unroll
    for (int o = 32; o; o >>= 1) m = fmaxf(m, __shfl_xor(m, o, 64));

    float s = 0.f;
#pragma unroll
    for (int i = 0; i < 4; ++i) {
        v[i].x = __expf(v[i].x - m);
        v[i].y = __expf(v[i].y - m);
        v[i].z = __expf(v[i].z - m);
        v[i].w = __expf(v[i].w - m);
        s += v[i].x + v[i].y + v[i].z + v[i].w;
    }
#pragma unroll
    for (int o = 32; o; o >>= 1) s += __shfl_xor(s, o, 64);

    const float inv = 1.0f / s;
#pragma unroll
    for (int i = 0; i < 4; ++i) {
        v[i].x *= inv; v[i].y *= inv; v[i].z *= inv; v[i].w *= inv;
        *(float4*)&p[i * 256 + lane * 4] = v[i];
        if (Sb) {
            bf16x4 b;
            b[0] = (bf16_t)v[i].x; b[1] = (bf16_t)v[i].y;
            b[2] = (bf16_t)v[i].z; b[3] = (bf16_t)v[i].w;
            *(bf16x4*)&Sb[row * (long)TENC + i * 256 + lane * 4] = b;
        }
    }
}

// ---------------------------------------------------------------------------
// fp32 fallback GEMM (kept as ws-size safety net)
#define TILE_M 64
#define TILE_N 64
#define TILE_K 16
template<bool B_TRANS, bool ADD_BIAS>
__global__ __launch_bounds__(256)
void gemm_f32(const float* __restrict__ A, const float* __restrict__ Bm,
              const float* __restrict__ bias, float* __restrict__ C,
              int M, int N, int K, int lda, int ldb,
              long strideA, long strideB, long strideC)
{
    __shared__ float As[TILE_K][TILE_M + 4];
    __shared__ float Bs[TILE_K][TILE_N + 4];
    const int b = blockIdx.z;
    A += (long)b * strideA; Bm += (long)b * strideB; C += (long)b * strideC;
    const int tid = threadIdx.x;
    const int tx = tid & 15, ty = tid >> 4;
    const int row0 = blockIdx.y * TILE_M, col0 = blockIdx.x * TILE_N;
    const int am = tid >> 2, ak = (tid & 3) * 4;
    float acc[4][4] = {};
    for (int kt = 0; kt < K; kt += TILE_K) {
        float4 a4 = *(const float4*)&A[(long)(row0 + am) * lda + kt + ak];
        float4 b4;
        if (B_TRANS) b4 = *(const float4*)&Bm[(long)(col0 + am) * ldb + kt + ak];
        else {
            const int bk_ = tid >> 4, bn = (tid & 15) * 4;
            b4 = *(const float4*)&Bm[(long)(kt + bk_) * ldb + col0 + bn];
        }
        __syncthreads();
        As[ak + 0][am] = a4.x; As[ak + 1][am] = a4.y;
        As[ak + 2][am] = a4.z; As[ak + 3][am] = a4.w;
        if (B_TRANS) {
            Bs[ak + 0][am] = b4.x; Bs[ak + 1][am] = b4.y;
            Bs[ak + 2][am] = b4.z; Bs[ak + 3][am] = b4.w;
        } else {
            const int bk_ = tid >> 4, bn = (tid & 15) * 4;
            *(float4*)&Bs[bk_][bn] = b4;
        }
        __syncthreads();
#pragma unroll
        for (int k = 0; k < TILE_K; ++k) {
            float4 av = *(const float4*)&As[k][ty * 4];
            float4 bv4 = *(const float4*)&Bs[k][tx * 4];
            float ar[4] = {av.x, av.y, av.z, av.w};
            float br[4] = {bv4.x, bv4.y, bv4.z, bv4.w};
#pragma unroll
            for (int i = 0; i < 4; ++i)
#pragma unroll
                for (int j = 0; j < 4; ++j)
                    acc[i][j] = fmaf(ar[i], br[j], acc[i][j]);
        }
    }
    float4 bias4 = make_float4(0.f, 0.f, 0.f, 0.f);
    if (ADD_BIAS) bias4 = *(const float4*)&bias[col0 + tx * 4];
#pragma unroll
    for (int i = 0; i < 4; ++i) {
        float4 o;
        o.x = acc[i][0] + bias4.x; o.y = acc[i][1] + bias4.y;
        o.z = acc[i][2] + bias4.z; o.w = acc[i][3] + bias4.w;
        *(float4*)&C[(long)(row0 + ty * 4 + i) * N + col0 + tx * 4] = o;
    }
}

// ---------------------------------------------------------------------------
extern "C" void kernel_launch(void* const* d_in, const int* in_sizes, int n_in,
                              void* d_out, int out_size, void* d_ws, size_t ws_size,
                              hipStream_t stream)
{
    const float* enc = (const float*)d_in[0];
    const float* dec = (const float*)d_in[1];
    const float* Wk  = (const float*)d_in[2];
    const float* Wv  = (const float*)d_in[4];
    const float* bv  = (const float*)d_in[5];

    const long nE = (long)BB * TENC * DDIM;   // 16777216
    const long nD = (long)BB * TDEC * NST;    // 8388608
    const long nW = (long)DDIM * NST;         // 262144

    float* ctx   = (float*)d_out;             // [32,512,512]
    float* attnF = ctx + nD;                  // [32,512,1024]

    const size_t need = 85458944;
    const dim3 blk(256);

    if (ws_size < need) {
        float* ws = (float*)d_ws;
        gemm_f32<true, false><<<dim3(DDIM / 64, (BB * TDEC) / 64, 1), blk, 0, stream>>>(
            dec, Wk, nullptr, ws, BB * TDEC, DDIM, NST, NST, NST, 0, 0, 0);
        gemm_f32<true, false><<<dim3(TENC / 64, TDEC / 64, BB), blk, 0, stream>>>(
            ws, enc, nullptr, attnF, TDEC, TENC, DDIM, DDIM, DDIM,
            (long)TDEC * DDIM, (long)TENC * DDIM, (long)TDEC * TENC);
        softmax_rows<<<(BB * TDEC) / 4, blk, 0, stream>>>(attnF, nullptr);
        gemm_f32<false, false><<<dim3(DDIM / 64, TDEC / 64, BB), blk, 0, stream>>>(
            attnF, enc, nullptr, ws, TDEC, DDIM, TENC, TENC, DDIM,
            (long)TDEC * TENC, (long)TENC * DDIM, (long)TDEC * DDIM);
        gemm_f32<false, true><<<dim3(NST / 64, (BB * TDEC) / 64, 1), blk, 0, stream>>>(
            ws, Wv, bv, ctx, BB * TDEC, NST, DDIM, DDIM, NST, 0, 0, 0);
        return;
    }

    // ws layout (bytes)
    char* w = (char*)d_ws;
    bf16_t* Ehi  = (bf16_t*)(w);                 // later aliased: attn bf16
    bf16_t* Elo  = (bf16_t*)(w + 33554432);      // later aliased: enc^T bf16
    bf16_t* AE   = (bf16_t*)(w + 67108864);
    bf16_t* Wkhi = (bf16_t*)(w + 83886080);
    bf16_t* Wklo = (bf16_t*)(w + 84410368);
    bf16_t* WvT  = (bf16_t*)(w + 84934656);

    // scratch inside d_out (free until the owning GEMM writes it)
    bf16_t* Dhi   = (bf16_t*)attnF;              // dec hi/lo in attn region
    bf16_t* Dlo   = Dhi + nD;
    bf16_t* DKhi  = (bf16_t*)ctx;                // DK hi/lo in ctx region
    bf16_t* DKlo  = DKhi + nD;
    bf16_t* attnB = Ehi;
    bf16_t* ET    = Elo;

    // 1) conversions
    split_f32_bf16<<<(unsigned)((nD / 4 + 255) / 256), blk, 0, stream>>>(dec, Dhi, Dlo, nD / 4);
    split_f32_bf16<<<(unsigned)((nW / 4 + 255) / 256), blk, 0, stream>>>(Wk, Wkhi, Wklo, nW / 4);
    split_f32_bf16<<<(unsigned)((nE / 4 + 255) / 256), blk, 0, stream>>>(enc, Ehi, Elo, nE / 4);
    transpose_to_bf16<float><<<dim3(8, 8, 1), blk, 0, stream>>>(
        Wv, WvT, DDIM, NST, 0, 0);

    // 2) DK = dec @ Wk^T   (split, A-direct) -> split bf16 into ctx region
    gemm_split4<1><<<dim3(DDIM / 128, (BB * TDEC) / 128, 1), blk, 0, stream>>>(
        Dhi, Dlo, Wkhi, Wklo, DKhi, DKlo,
        BB * TDEC, DDIM, NST, 0, 0, 0);

    // 3) score = DK @ enc^T  (split, A-direct) -> f32 attn region
    gemm_split4<0><<<dim3(TENC / 128, TDEC / 128, BB), blk, 0, stream>>>(
        DKhi, DKlo, Ehi, Elo, attnF, nullptr,
        TDEC, TENC, DDIM,
        (long)TDEC * DDIM, (long)TENC * DDIM, (long)TDEC * TENC);

    // 4) enc^T bf16 (overwrites Elo — dead after score GEMM)
    transpose_to_bf16<bf16_t><<<dim3(DDIM / 64, TENC / 64, BB), blk, 0, stream>>>(
        Ehi, ET, TENC, DDIM, (long)TENC * DDIM, (long)DDIM * TENC);

    // 5) softmax (f32 in place; bf16 copy overwrites Ehi — dead)
    softmax_rows<<<(BB * TDEC) / 4, blk, 0, stream>>>(attnF, attnB);

    // 6) AE = attn @ enc  (plain bf16 + T1) -> bf16 ws
    mfma_gemm<2><<<dim3(DDIM / 128, TDEC / 128, BB), blk, 0, stream>>>(
        attnB, ET, nullptr, AE,
        TDEC, DDIM, TENC,
        (long)TDEC * TENC, (long)DDIM * TENC, (long)TDEC * DDIM);

    // 7) ctx = AE @ Wv^T' + bv  (plain bf16 + T1) -> f32 ctx
    mfma_gemm<3><<<dim3(NST / 128, (BB * TDEC) / 128, 1), blk, 0, stream>>>(
        AE, WvT, bv, ctx,
        BB * TDEC, NST, DDIM, 0, 0, 0);
}

// Round 7
// 196.398 us; speedup vs baseline: 1.3071x; 1.3071x over previous
//
#include <hip/hip_runtime.h>
#include <math.h>

#define BB    32
#define TENC  1024
#define TDEC  512
#define DDIM  512
#define NST   512

typedef __bf16 bf16_t;
typedef __bf16 bf16x8 __attribute__((ext_vector_type(8)));
typedef __bf16 bf16x4 __attribute__((ext_vector_type(4)));
typedef float  f32x4  __attribute__((ext_vector_type(4)));

#define GLOAD_LDS16(gp, lp) __builtin_amdgcn_global_load_lds( \
    (const __attribute__((address_space(1))) unsigned int*)(const void*)(gp), \
    (__attribute__((address_space(3))) unsigned int*)(lp), 16, 0, 0)

static __device__ __forceinline__ f32x4 MFMA16(bf16x8 a, bf16x8 b, f32x4 c) {
    return __builtin_amdgcn_mfma_f32_16x16x32_bf16(a, b, c, 0, 0, 0);
}

// ---------------------------------------------------------------------------
// Split f32 -> bf16 hi/lo (only used for Wk now)
__global__ __launch_bounds__(256)
void split_f32_bf16(const float* __restrict__ x, bf16_t* __restrict__ hi,
                    bf16_t* __restrict__ lo, long n4)
{
    long i = (long)blockIdx.x * 256 + threadIdx.x;
    if (i >= n4) return;
    float4 v = *(const float4*)&x[i * 4];
    float f[4] = {v.x, v.y, v.z, v.w};
    bf16x4 h, l;
#pragma unroll
    for (int e = 0; e < 4; ++e) {
        bf16_t hh = (bf16_t)f[e];
        h[e] = hh;
        l[e] = (bf16_t)(f[e] - (float)hh);
    }
    *(bf16x4*)&hi[i * 4] = h;
    *(bf16x4*)&lo[i * 4] = l;
}

// ---------------------------------------------------------------------------
// Tiled transpose f32 -> bf16 (only used for Wv)
__global__ __launch_bounds__(256)
void transpose_to_bf16(const float* __restrict__ in, bf16_t* __restrict__ out,
                       int R, int C)
{
    __shared__ bf16_t tile[64][65];
    const int c0 = blockIdx.x * 64, r0 = blockIdx.y * 64;
    const int t = threadIdx.x;
    const int rr = t >> 4;
    const int cc = (t & 15) * 4;
#pragma unroll
    for (int p = 0; p < 4; ++p) {
        int r = rr + p * 16;
        float4 v = *(const float4*)&in[(long)(r0 + r) * C + c0 + cc];
        tile[r][cc + 0] = (bf16_t)v.x;
        tile[r][cc + 1] = (bf16_t)v.y;
        tile[r][cc + 2] = (bf16_t)v.z;
        tile[r][cc + 3] = (bf16_t)v.w;
    }
    __syncthreads();
    const int dr = t >> 2;
    const int tc = (t & 3) * 16;
    bf16_t tmp[16];
#pragma unroll
    for (int e = 0; e < 16; ++e) tmp[e] = tile[tc + e][dr];
    *(bf16x8*)&out[(long)(c0 + dr) * R + r0 + tc]     = *(bf16x8*)&tmp[0];
    *(bf16x8*)&out[(long)(c0 + dr) * R + r0 + tc + 8] = *(bf16x8*)&tmp[8];
}

// ---------------------------------------------------------------------------
// Unified MFMA GEMM: C[M,N] = opA[M,K] @ opB[N,K]^T (+bias), K-contiguous rows.
// Operand MODES: 0 = gload_lds single bf16, 1 = gload_lds split pair (hi+lo),
//                2 = reg-staged f32 -> bf16 (single), 3 = reg-staged f32 -> hi+lo.
// Exactly one operand is reg-staged (2/3) in every instantiation used.
// If both operands have lo parts: 3-term split MFMA (hh+hl+lh), else 1-term.
// BM=BN=128, BK=32, 4 waves (2x2, wave-tile 64x64), double-buffered swizzled
// LDS (2 blocks/CU for split kernels). Counted vmcnt keeps prefetch in flight.
// EPI: 0=f32, 1=split bf16 (C0=hi,C1=lo), 2=bf16, 3=f32+bias.
template<int AM, int BM, int EPI>
__global__ __launch_bounds__(256)
void gemm_u(const float* __restrict__ Af, const bf16_t* __restrict__ Ahi,
            const bf16_t* __restrict__ Alo,
            const float* __restrict__ Bf, const bf16_t* __restrict__ Bhi,
            const bf16_t* __restrict__ Blo,
            const float* __restrict__ bias, void* __restrict__ C0,
            void* __restrict__ C1,
            int M, int N, int K,
            long sAf, long sAb, long sBf, long sBb, long sC)
{
    constexpr bool AG = (AM < 2), BG = (BM < 2);        // gload operand?
    constexpr bool APAIR = (AM == 1 || AM == 3);
    constexpr bool BPAIR = (BM == 1 || BM == 3);
    constexpr bool SPL = APAIR && BPAIR;                // 3-term split math
    constexpr int ASZ = APAIR ? 8192 : 4096;
    constexpr int BSZ = BPAIR ? 8192 : 4096;
    constexpr int NGL = (AG ? (APAIR ? 4 : 2) : 0) + (BG ? (BPAIR ? 4 : 2) : 0);

    __shared__ bf16_t lds[2][ASZ + BSZ];
    // layout per buffer: Ahi[0,4096) Alo[4096,8192)|absent  Bhi[ASZ,+4096) Blo[ASZ+4096,..)

    const int tid  = threadIdx.x;
    const int wave = tid >> 6;
    const int lane = tid & 63;

    // T1: bijective XCD swizzle (all grids are multiples of 8)
    const int gx = gridDim.x, gy = gridDim.y;
    const long nwg = (long)gx * gy * gridDim.z;
    const long fo  = ((long)blockIdx.z * gy + blockIdx.y) * gx + blockIdx.x;
    const long f2 = (fo & 7) * (nwg >> 3) + (fo >> 3);
    const int bx  = (int)(f2 % gx);
    const int by  = (int)((f2 / gx) % gy);
    const long bz = f2 / ((long)gx * gy);

    const int row0 = by * 128;
    const int col0 = bx * 128;

    // gload staging indices (256 thr x 16B = 64 rows x 32k per issue)
    const int srow  = wave * 16 + (lane >> 2);            // 0..63
    const int sslot = (lane & 3) ^ ((srow >> 1) & 3);
    const int wdst  = wave * 512;                          // elems within issue chunk

    // reg staging indices (256 thr x float4 = 32 rows x 32k per chunk, 4 chunks)
    const int rrow = tid >> 3;            // 0..31
    const int rk4  = (tid & 7) * 4;       // f32 col offset
    const int rg   = rk4 >> 3;            // 8-elem granule
    const int rh4  = rk4 & 4;             // half offset within granule

    // fragment read offsets (swizzled), wave-tile 64x64 at (wr,wc)
    const int fr = lane & 15;
    const int q  = lane >> 4;
    const int wr = (wave >> 1) * 64;
    const int wc = (wave & 1) * 64;
    int aro[4], bro[4];
#pragma unroll
    for (int i = 0; i < 4; ++i) {
        const int r = wr + i * 16 + fr;
        aro[i] = r * 32 + ((q ^ ((r >> 1) & 3)) * 8);
    }
#pragma unroll
    for (int j = 0; j < 4; ++j) {
        const int r = wc + j * 16 + fr;
        bro[j] = r * 32 + ((q ^ ((r >> 1) & 3)) * 8);
    }

    // operand bases
    const float*  AfB = (AM >= 2) ? Af  + bz * sAf : nullptr;
    const bf16_t* AhB = AG        ? Ahi + bz * sAb : nullptr;
    const bf16_t* AlB = (AM == 1) ? Alo + bz * sAb : nullptr;
    const float*  BfB = (BM >= 2) ? Bf  + bz * sBf : nullptr;
    const bf16_t* BhB = BG        ? Bhi + bz * sBb : nullptr;
    const bf16_t* BlB = (BM == 1) ? Blo + bz * sBb : nullptr;

    f32x4 acc[4][4] = {};
    float4 rS[4];
    const int NT = K >> 5;

    // ---- staging helpers --------------------------------------------------
    auto stageG = [&](bf16_t* buf, int kt) {
        if constexpr (AG) {
#pragma unroll
            for (int c = 0; c < 2; ++c) {
                const long go = (long)(row0 + c * 64 + srow) * K + kt + sslot * 8;
                GLOAD_LDS16(AhB + go, &buf[c * 2048 + wdst]);
                if constexpr (AM == 1)
                    GLOAD_LDS16(AlB + go, &buf[4096 + c * 2048 + wdst]);
            }
        }
        if constexpr (BG) {
#pragma unroll
            for (int c = 0; c < 2; ++c) {
                const long go = (long)(col0 + c * 64 + srow) * K + kt + sslot * 8;
                GLOAD_LDS16(BhB + go, &buf[ASZ + c * 2048 + wdst]);
                if constexpr (BM == 1)
                    GLOAD_LDS16(BlB + go, &buf[ASZ + 4096 + c * 2048 + wdst]);
            }
        }
    };
    auto loadR = [&](int kt) {
        const float* src = (AM >= 2) ? AfB : BfB;
        const int base0 = (AM >= 2) ? row0 : col0;
#pragma unroll
        for (int i = 0; i < 4; ++i)
            rS[i] = *(const float4*)&src[(long)(base0 + i * 32 + rrow) * K + kt + rk4];
    };
    auto writeR = [&](bf16_t* buf) {
        constexpr int offH = (AM >= 2) ? 0 : ASZ;
        constexpr int offL = offH + 4096;
        constexpr bool splitme = (AM == 3) || (BM == 3);
#pragma unroll
        for (int i = 0; i < 4; ++i) {
            const int row = i * 32 + rrow;
            const int eo  = row * 32 + ((rg ^ ((row >> 1) & 3)) * 8) + rh4;
            float f[4] = {rS[i].x, rS[i].y, rS[i].z, rS[i].w};
            bf16x4 h4, l4;
#pragma unroll
            for (int e = 0; e < 4; ++e) {
                bf16_t hh = (bf16_t)f[e];
                h4[e] = hh;
                if (splitme) l4[e] = (bf16_t)(f[e] - (float)hh);
            }
            *(bf16x4*)&buf[offH + eo] = h4;
            if constexpr (splitme) *(bf16x4*)&buf[offL + eo] = l4;
        }
    };
    // -----------------------------------------------------------------------

    // prologue: tile 0 staged into buf0; reg set advanced to tile 1
    loadR(0);
    stageG(lds[0], 0);
    writeR(lds[0]);                 // implicit wait on rS(0); gloads(0) stay in flight
    if (NT > 1) loadR(32);
    asm volatile("s_waitcnt lgkmcnt(0)" ::: "memory");
    __builtin_amdgcn_s_barrier();
    __builtin_amdgcn_sched_barrier(0);

    for (int t = 0; t < NT; ++t) {
        bf16_t* cur = lds[t & 1];
        bf16_t* nxt = lds[(t & 1) ^ 1];
        const bool pf = (t + 1 < NT);

        if (pf) {
            writeR(nxt);                       // consumes rS(t+1): drains gloads(t) (FIFO)
            stageG(nxt, (t + 1) << 5);         // tile t+1 gloads -> in flight
            if (t + 2 < NT) loadR((t + 2) << 5);
            // explicit counted drain: allow only this iter's new issues outstanding
            if constexpr (NGL + 4 == 6)
                asm volatile("s_waitcnt vmcnt(6)" ::: "memory");
            else
                asm volatile("s_waitcnt vmcnt(8)" ::: "memory");
        } else {
            asm volatile("s_waitcnt vmcnt(0)" ::: "memory");
        }
        asm volatile("s_waitcnt lgkmcnt(0)" ::: "memory");
        __builtin_amdgcn_s_barrier();
        __builtin_amdgcn_sched_barrier(0);

        bf16x8 aH[4], bH[4], aL[4], bL[4];
#pragma unroll
        for (int i = 0; i < 4; ++i) {
            aH[i] = *(const bf16x8*)&cur[aro[i]];
            if constexpr (SPL) aL[i] = *(const bf16x8*)&cur[4096 + aro[i]];
        }
#pragma unroll
        for (int j = 0; j < 4; ++j) {
            bH[j] = *(const bf16x8*)&cur[ASZ + bro[j]];
            if constexpr (SPL) bL[j] = *(const bf16x8*)&cur[ASZ + 4096 + bro[j]];
        }

        __builtin_amdgcn_s_setprio(1);
#pragma unroll
        for (int j = 0; j < 4; ++j)
#pragma unroll
            for (int i = 0; i < 4; ++i) {
                acc[i][j] = MFMA16(aH[i], bH[j], acc[i][j]);
                if constexpr (SPL) {
                    acc[i][j] = MFMA16(aH[i], bL[j], acc[i][j]);
                    acc[i][j] = MFMA16(aL[i], bH[j], acc[i][j]);
                }
            }
        __builtin_amdgcn_s_setprio(0);
        __builtin_amdgcn_sched_barrier(0);
        __builtin_amdgcn_s_barrier();
    }

    // epilogue (C/D layout: col = lane&15, row = (lane>>4)*4 + reg)
    const int frow = q * 4;
#pragma unroll
    for (int i = 0; i < 4; ++i) {
        const int rgl = row0 + wr + i * 16 + frow;
#pragma unroll
        for (int j = 0; j < 4; ++j) {
            const int cg = col0 + wc + j * 16 + fr;
            if constexpr (EPI == 0) {
                float* C = (float*)C0 + bz * sC;
#pragma unroll
                for (int r = 0; r < 4; ++r)
                    C[(long)(rgl + r) * N + cg] = acc[i][j][r];
            } else if constexpr (EPI == 1) {
                bf16_t* Ch = (bf16_t*)C0 + bz * sC;
                bf16_t* Cl = (bf16_t*)C1 + bz * sC;
#pragma unroll
                for (int r = 0; r < 4; ++r) {
                    float v = acc[i][j][r];
                    bf16_t h = (bf16_t)v;
                    Ch[(long)(rgl + r) * N + cg] = h;
                    Cl[(long)(rgl + r) * N + cg] = (bf16_t)(v - (float)h);
                }
            } else if constexpr (EPI == 2) {
                bf16_t* Ch = (bf16_t*)C0 + bz * sC;
#pragma unroll
                for (int r = 0; r < 4; ++r)
                    Ch[(long)(rgl + r) * N + cg] = (bf16_t)acc[i][j][r];
            } else {
                float* C = (float*)C0 + bz * sC;
                const float badd = bias[cg];
#pragma unroll
                for (int r = 0; r < 4; ++r)
                    C[(long)(rgl + r) * N + cg] = acc[i][j][r] + badd;
            }
        }
    }
}

// ---------------------------------------------------------------------------
// Row softmax over length-1024 rows, in place (f32).
__global__ __launch_bounds__(256)
void softmax_rows(float* __restrict__ S)
{
    const long row = (long)blockIdx.x * 4 + (threadIdx.x >> 6);
    const int lane = threadIdx.x & 63;
    float* p = S + row * (long)TENC;

    float4 v[4];
    float m = -INFINITY;
#pragma unroll
    for (int i = 0; i < 4; ++i) {
        v[i] = *(const float4*)&p[i * 256 + lane * 4];
        m = fmaxf(fmaxf(fmaxf(v[i].x, v[i].y), fmaxf(v[i].z, v[i].w)), m);
    }
#pragma unroll
    for (int o = 32; o; o >>= 1) m = fmaxf(m, __shfl_xor(m, o, 64));

    float s = 0.f;
#pragma unroll
    for (int i = 0; i < 4; ++i) {
        v[i].x = __expf(v[i].x - m);
        v[i].y = __expf(v[i].y - m);
        v[i].z = __expf(v[i].z - m);
        v[i].w = __expf(v[i].w - m);
        s += v[i].x + v[i].y + v[i].z + v[i].w;
    }
#pragma unroll
    for (int o = 32; o; o >>= 1) s += __shfl_xor(s, o, 64);

    const float inv = 1.0f / s;
#pragma unroll
    for (int i = 0; i < 4; ++i) {
        v[i].x *= inv; v[i].y *= inv; v[i].z *= inv; v[i].w *= inv;
        *(float4*)&p[i * 256 + lane * 4] = v[i];
    }
}

// ---------------------------------------------------------------------------
// fp32 fallback GEMM (safety net for tiny ws)
#define TILE_M 64
#define TILE_N 64
#define TILE_K 16
template<bool B_TRANS, bool ADD_BIAS>
__global__ __launch_bounds__(256)
void gemm_f32(const float* __restrict__ A, const float* __restrict__ Bm,
              const float* __restrict__ bias, float* __restrict__ C,
              int M, int N, int K, int lda, int ldb,
              long strideA, long strideB, long strideC)
{
    __shared__ float As[TILE_K][TILE_M + 4];
    __shared__ float Bs[TILE_K][TILE_N + 4];
    const int b = blockIdx.z;
    A += (long)b * strideA; Bm += (long)b * strideB; C += (long)b * strideC;
    const int tid = threadIdx.x;
    const int tx = tid & 15, ty = tid >> 4;
    const int row0 = blockIdx.y * TILE_M, col0 = blockIdx.x * TILE_N;
    const int am = tid >> 2, ak = (tid & 3) * 4;
    float acc[4][4] = {};
    for (int kt = 0; kt < K; kt += TILE_K) {
        float4 a4 = *(const float4*)&A[(long)(row0 + am) * lda + kt + ak];
        float4 b4;
        if (B_TRANS) b4 = *(const float4*)&Bm[(long)(col0 + am) * ldb + kt + ak];
        else {
            const int bk_ = tid >> 4, bn = (tid & 15) * 4;
            b4 = *(const float4*)&Bm[(long)(kt + bk_) * ldb + col0 + bn];
        }
        __syncthreads();
        As[ak + 0][am] = a4.x; As[ak + 1][am] = a4.y;
        As[ak + 2][am] = a4.z; As[ak + 3][am] = a4.w;
        if (B_TRANS) {
            Bs[ak + 0][am] = b4.x; Bs[ak + 1][am] = b4.y;
            Bs[ak + 2][am] = b4.z; Bs[ak + 3][am] = b4.w;
        } else {
            const int bk_ = tid >> 4, bn = (tid & 15) * 4;
            *(float4*)&Bs[bk_][bn] = b4;
        }
        __syncthreads();
#pragma unroll
        for (int k = 0; k < TILE_K; ++k) {
            float4 av = *(const float4*)&As[k][ty * 4];
            float4 bv4 = *(const float4*)&Bs[k][tx * 4];
            float ar[4] = {av.x, av.y, av.z, av.w};
            float br[4] = {bv4.x, bv4.y, bv4.z, bv4.w};
#pragma unroll
            for (int i = 0; i < 4; ++i)
#pragma unroll
                for (int j = 0; j < 4; ++j)
                    acc[i][j] = fmaf(ar[i], br[j], acc[i][j]);
        }
    }
    float4 bias4 = make_float4(0.f, 0.f, 0.f, 0.f);
    if (ADD_BIAS) bias4 = *(const float4*)&bias[col0 + tx * 4];
#pragma unroll
    for (int i = 0; i < 4; ++i) {
        float4 o;
        o.x = acc[i][0] + bias4.x; o.y = acc[i][1] + bias4.y;
        o.z = acc[i][2] + bias4.z; o.w = acc[i][3] + bias4.w;
        *(float4*)&C[(long)(row0 + ty * 4 + i) * N + col0 + tx * 4] = o;
    }
}

// ---------------------------------------------------------------------------
extern "C" void kernel_launch(void* const* d_in, const int* in_sizes, int n_in,
                              void* d_out, int out_size, void* d_ws, size_t ws_size,
                              hipStream_t stream)
{
    const float* enc = (const float*)d_in[0];   // [32,1024,512]
    const float* dec = (const float*)d_in[1];   // [32,512,512]
    const float* Wk  = (const float*)d_in[2];   // [512,512]
    const float* Wv  = (const float*)d_in[4];   // [512,512]
    const float* bv  = (const float*)d_in[5];   // [512]

    const long nD = (long)BB * TDEC * NST;      // 8388608
    const long nW = (long)DDIM * NST;           // 262144

    float* ctx   = (float*)d_out;               // [32,512,512]
    float* attnF = ctx + nD;                    // [32,512,1024]

    const size_t need = 35127296;
    const dim3 blk(256);

    if (ws_size < need) {
        float* ws = (float*)d_ws;
        gemm_f32<true, false><<<dim3(DDIM / 64, (BB * TDEC) / 64, 1), blk, 0, stream>>>(
            dec, Wk, nullptr, ws, BB * TDEC, DDIM, NST, NST, NST, 0, 0, 0);
        gemm_f32<true, false><<<dim3(TENC / 64, TDEC / 64, BB), blk, 0, stream>>>(
            ws, enc, nullptr, attnF, TDEC, TENC, DDIM, DDIM, DDIM,
            (long)TDEC * DDIM, (long)TENC * DDIM, (long)TDEC * TENC);
        softmax_rows<<<(BB * TDEC) / 4, blk, 0, stream>>>(attnF);
        gemm_f32<false, false><<<dim3(DDIM / 64, TDEC / 64, BB), blk, 0, stream>>>(
            attnF, enc, nullptr, ws, TDEC, DDIM, TENC, TENC, DDIM,
            (long)TDEC * TENC, (long)TENC * DDIM, (long)TDEC * DDIM);
        gemm_f32<false, true><<<dim3(NST / 64, (BB * TDEC) / 64, 1), blk, 0, stream>>>(
            ws, Wv, bv, ctx, BB * TDEC, NST, DDIM, DDIM, NST, 0, 0, 0);
        return;
    }

    // ws layout (bytes)
    char* w = (char*)d_ws;
    bf16_t* EVT  = (bf16_t*)(w);                 // [32][512][1024] bf16 = 33.55MB
    bf16_t* Wkhi = (bf16_t*)(w + 33554432);
    bf16_t* Wklo = (bf16_t*)(w + 34078720);
    bf16_t* WvT  = (bf16_t*)(w + 34603008);

    // DK split lives in the not-yet-written ctx output region (exactly 33.55MB)
    bf16_t* DKhi = (bf16_t*)ctx;
    bf16_t* DKlo = DKhi + nD;

    // 1) tiny weight preps
    split_f32_bf16<<<(unsigned)(nW / 4 / 256), blk, 0, stream>>>(Wk, Wkhi, Wklo, nW / 4);
    transpose_to_bf16<<<dim3(NST / 64, DDIM / 64, 1), blk, 0, stream>>>(Wv, WvT, DDIM, NST);

    // 2) DK = dec @ Wk^T  (A: dec f32 reg-split; B: Wk split gload) -> split bf16
    gemm_u<3, 1, 1><<<dim3(DDIM / 128, (BB * TDEC) / 128, 1), blk, 0, stream>>>(
        dec, nullptr, nullptr, nullptr, Wkhi, Wklo, nullptr, DKhi, DKlo,
        BB * TDEC, DDIM, NST, 0, 0, 0, 0, 0);

    // 3) score = DK @ enc^T  (A: DK split gload; B: enc f32 reg-split) -> f32 attn
    gemm_u<1, 3, 0><<<dim3(TENC / 128, TDEC / 128, BB), blk, 0, stream>>>(
        nullptr, DKhi, DKlo, enc, nullptr, nullptr, nullptr, attnF, nullptr,
        TDEC, TENC, DDIM,
        0, (long)TDEC * DDIM, (long)TENC * DDIM, 0, (long)TDEC * TENC);

    // 4) EV^T = Wv^T @ enc^T  (A: WvT bf16 gload; B: enc f32 reg-bf16) -> bf16 ws
    gemm_u<0, 2, 2><<<dim3(TENC / 128, NST / 128, BB), blk, 0, stream>>>(
        nullptr, WvT, nullptr, enc, nullptr, nullptr, nullptr, EVT, nullptr,
        NST, TENC, DDIM,
        0, 0, (long)TENC * DDIM, 0, (long)NST * TENC);

    // 5) softmax rows, in place f32
    softmax_rows<<<(BB * TDEC) / 4, blk, 0, stream>>>(attnF);

    // 6) ctx = attn @ EV + bv  (A: attn f32 reg-bf16; B: EVT gload) -> f32 ctx
    //    (overwrites the DK scratch — DK dead after step 3)
    gemm_u<2, 0, 3><<<dim3(NST / 128, TDEC / 128, BB), blk, 0, stream>>>(
        attnF, nullptr, nullptr, nullptr, EVT, nullptr, bv, ctx, nullptr,
        TDEC, NST, TENC,
        (long)TDEC * TENC, 0, 0, (long)NST * TENC, (long)TDEC * NST);
}

// Round 8
// 189.482 us; speedup vs baseline: 1.3548x; 1.0365x over previous
//
#include <hip/hip_runtime.h>
#include <math.h>

#define BB    32
#define TENC  1024
#define TDEC  512
#define DDIM  512
#define NST   512

typedef __bf16 bf16_t;
typedef __bf16 bf16x8 __attribute__((ext_vector_type(8)));
typedef __bf16 bf16x4 __attribute__((ext_vector_type(4)));
typedef float  f32x4  __attribute__((ext_vector_type(4)));

#define GLOAD_LDS16(gp, lp) __builtin_amdgcn_global_load_lds( \
    (const __attribute__((address_space(1))) unsigned int*)(const void*)(gp), \
    (__attribute__((address_space(3))) unsigned int*)(lp), 16, 0, 0)

static __device__ __forceinline__ f32x4 MFMA16(bf16x8 a, bf16x8 b, f32x4 c) {
    return __builtin_amdgcn_mfma_f32_16x16x32_bf16(a, b, c, 0, 0, 0);
}

// ---------------------------------------------------------------------------
// Split f32 -> bf16 hi/lo (only used for Wk)
__global__ __launch_bounds__(256)
void split_f32_bf16(const float* __restrict__ x, bf16_t* __restrict__ hi,
                    bf16_t* __restrict__ lo, long n4)
{
    long i = (long)blockIdx.x * 256 + threadIdx.x;
    if (i >= n4) return;
    float4 v = *(const float4*)&x[i * 4];
    float f[4] = {v.x, v.y, v.z, v.w};
    bf16x4 h, l;
#pragma unroll
    for (int e = 0; e < 4; ++e) {
        bf16_t hh = (bf16_t)f[e];
        h[e] = hh;
        l[e] = (bf16_t)(f[e] - (float)hh);
    }
    *(bf16x4*)&hi[i * 4] = h;
    *(bf16x4*)&lo[i * 4] = l;
}

// ---------------------------------------------------------------------------
// Tiled transpose f32 -> bf16 (only used for Wv)
__global__ __launch_bounds__(256)
void transpose_to_bf16(const float* __restrict__ in, bf16_t* __restrict__ out,
                       int R, int C)
{
    __shared__ bf16_t tile[64][65];
    const int c0 = blockIdx.x * 64, r0 = blockIdx.y * 64;
    const int t = threadIdx.x;
    const int rr = t >> 4;
    const int cc = (t & 15) * 4;
#pragma unroll
    for (int p = 0; p < 4; ++p) {
        int r = rr + p * 16;
        float4 v = *(const float4*)&in[(long)(r0 + r) * C + c0 + cc];
        tile[r][cc + 0] = (bf16_t)v.x;
        tile[r][cc + 1] = (bf16_t)v.y;
        tile[r][cc + 2] = (bf16_t)v.z;
        tile[r][cc + 3] = (bf16_t)v.w;
    }
    __syncthreads();
    const int dr = t >> 2;
    const int tc = (t & 3) * 16;
    bf16_t tmp[16];
#pragma unroll
    for (int e = 0; e < 16; ++e) tmp[e] = tile[tc + e][dr];
    *(bf16x8*)&out[(long)(c0 + dr) * R + r0 + tc]     = *(bf16x8*)&tmp[0];
    *(bf16x8*)&out[(long)(c0 + dr) * R + r0 + tc + 8] = *(bf16x8*)&tmp[8];
}

// ---------------------------------------------------------------------------
// Unified MFMA GEMM: C[M,N] = opA[M,K] @ opB[N,K]^T (+bias), K-contiguous rows.
// Operand MODES: 0 = gload_lds single bf16, 1 = gload_lds split pair (hi+lo),
//                2 = reg-staged f32 -> bf16 (single), 3 = reg-staged f32 -> hi+lo.
// R8 schedule: staging (cvt+ds_write+gload-issue+reg-load-issue) is placed in
// the SAME unfenced region as the MFMA cluster -> VALU/DS/VMEM co-issue with
// MFMA. Serial remainder per tile: vmcnt(4)+lgkm0+barrier+frag ds_reads+barrier.
// EPI: 0=f32, 1=split bf16 (C0=hi,C1=lo), 2=bf16, 3=f32+bias.
template<int AM, int BM, int EPI>
__global__ __launch_bounds__(256)
void gemm_u(const float* __restrict__ Af, const bf16_t* __restrict__ Ahi,
            const bf16_t* __restrict__ Alo,
            const float* __restrict__ Bf, const bf16_t* __restrict__ Bhi,
            const bf16_t* __restrict__ Blo,
            const float* __restrict__ bias, void* __restrict__ C0,
            void* __restrict__ C1,
            int M, int N, int K,
            long sAf, long sAb, long sBf, long sBb, long sC)
{
    constexpr bool AG = (AM < 2), BG = (BM < 2);        // gload operand?
    constexpr bool APAIR = (AM == 1 || AM == 3);
    constexpr bool BPAIR = (BM == 1 || BM == 3);
    constexpr bool SPL = APAIR && BPAIR;                // 3-term split math
    constexpr int ASZ = APAIR ? 8192 : 4096;
    constexpr int BSZ = BPAIR ? 8192 : 4096;

    __shared__ bf16_t lds[2][ASZ + BSZ];
    // per buffer: Ahi[0,4096) Alo[4096,8192)|absent  Bhi[ASZ,+4096) Blo[ASZ+4096,..)

    const int tid  = threadIdx.x;
    const int wave = tid >> 6;
    const int lane = tid & 63;

    // T1: bijective XCD swizzle (all grids are multiples of 8)
    const int gx = gridDim.x, gy = gridDim.y;
    const long nwg = (long)gx * gy * gridDim.z;
    const long fo  = ((long)blockIdx.z * gy + blockIdx.y) * gx + blockIdx.x;
    const long f2 = (fo & 7) * (nwg >> 3) + (fo >> 3);
    const int bx  = (int)(f2 % gx);
    const int by  = (int)((f2 / gx) % gy);
    const long bz = f2 / ((long)gx * gy);

    const int row0 = by * 128;
    const int col0 = bx * 128;

    // gload staging indices (256 thr x 16B = 64 rows x 32k per issue)
    const int srow  = wave * 16 + (lane >> 2);            // 0..63
    const int sslot = (lane & 3) ^ ((srow >> 1) & 3);
    const int wdst  = wave * 512;                          // elems within issue chunk

    // reg staging indices (256 thr x float4 = 32 rows x 32k per chunk, 4 chunks)
    const int rrow = tid >> 3;            // 0..31
    const int rk4  = (tid & 7) * 4;       // f32 col offset
    const int rg   = rk4 >> 3;            // 8-elem granule
    const int rh4  = rk4 & 4;             // half offset within granule

    // fragment read offsets (swizzled), wave-tile 64x64 at (wr,wc)
    const int fr = lane & 15;
    const int q  = lane >> 4;
    const int wr = (wave >> 1) * 64;
    const int wc = (wave & 1) * 64;
    int aro[4], bro[4];
#pragma unroll
    for (int i = 0; i < 4; ++i) {
        const int r = wr + i * 16 + fr;
        aro[i] = r * 32 + ((q ^ ((r >> 1) & 3)) * 8);
    }
#pragma unroll
    for (int j = 0; j < 4; ++j) {
        const int r = wc + j * 16 + fr;
        bro[j] = r * 32 + ((q ^ ((r >> 1) & 3)) * 8);
    }

    // operand bases
    const float*  AfB = (AM >= 2) ? Af  + bz * sAf : nullptr;
    const bf16_t* AhB = AG        ? Ahi + bz * sAb : nullptr;
    const bf16_t* AlB = (AM == 1) ? Alo + bz * sAb : nullptr;
    const float*  BfB = (BM >= 2) ? Bf  + bz * sBf : nullptr;
    const bf16_t* BhB = BG        ? Bhi + bz * sBb : nullptr;
    const bf16_t* BlB = (BM == 1) ? Blo + bz * sBb : nullptr;

    f32x4 acc[4][4] = {};
    float4 rS[4];
    bf16x8 aH[4], bH[4], aL[4], bL[4];
    const int NT = K >> 5;

    // ---- staging helpers --------------------------------------------------
    auto stageG = [&](bf16_t* buf, int kt) {
        if constexpr (AG) {
#pragma unroll
            for (int c = 0; c < 2; ++c) {
                const long go = (long)(row0 + c * 64 + srow) * K + kt + sslot * 8;
                GLOAD_LDS16(AhB + go, &buf[c * 2048 + wdst]);
                if constexpr (AM == 1)
                    GLOAD_LDS16(AlB + go, &buf[4096 + c * 2048 + wdst]);
            }
        }
        if constexpr (BG) {
#pragma unroll
            for (int c = 0; c < 2; ++c) {
                const long go = (long)(col0 + c * 64 + srow) * K + kt + sslot * 8;
                GLOAD_LDS16(BhB + go, &buf[ASZ + c * 2048 + wdst]);
                if constexpr (BM == 1)
                    GLOAD_LDS16(BlB + go, &buf[ASZ + 4096 + c * 2048 + wdst]);
            }
        }
    };
    auto loadR = [&](int kt) {
        const float* src = (AM >= 2) ? AfB : BfB;
        const int base0 = (AM >= 2) ? row0 : col0;
#pragma unroll
        for (int i = 0; i < 4; ++i)
            rS[i] = *(const float4*)&src[(long)(base0 + i * 32 + rrow) * K + kt + rk4];
    };
    auto writeR = [&](bf16_t* buf) {
        constexpr int offH = (AM >= 2) ? 0 : ASZ;
        constexpr int offL = offH + 4096;
        constexpr bool splitme = (AM == 3) || (BM == 3);
#pragma unroll
        for (int i = 0; i < 4; ++i) {
            const int row = i * 32 + rrow;
            const int eo  = row * 32 + ((rg ^ ((row >> 1) & 3)) * 8) + rh4;
            float f[4] = {rS[i].x, rS[i].y, rS[i].z, rS[i].w};
            bf16x4 h4, l4;
#pragma unroll
            for (int e = 0; e < 4; ++e) {
                bf16_t hh = (bf16_t)f[e];
                h4[e] = hh;
                if (splitme) l4[e] = (bf16_t)(f[e] - (float)hh);
            }
            *(bf16x4*)&buf[offH + eo] = h4;
            if constexpr (splitme) *(bf16x4*)&buf[offL + eo] = l4;
        }
    };
    auto readF = [&](const bf16_t* buf) {
#pragma unroll
        for (int i = 0; i < 4; ++i) {
            aH[i] = *(const bf16x8*)&buf[aro[i]];
            if constexpr (SPL) aL[i] = *(const bf16x8*)&buf[4096 + aro[i]];
        }
#pragma unroll
        for (int j = 0; j < 4; ++j) {
            bH[j] = *(const bf16x8*)&buf[ASZ + bro[j]];
            if constexpr (SPL) bL[j] = *(const bf16x8*)&buf[ASZ + 4096 + bro[j]];
        }
    };
    // -----------------------------------------------------------------------

    // prologue (NT >= 2 always: K is 512 or 1024)
    loadR(0);
    stageG(lds[0], 0);
    writeR(lds[0]);                 // waits rS(0); gloads(0) stay in flight behind it
    loadR(32);
    asm volatile("s_waitcnt vmcnt(4)" ::: "memory");   // gloads(0) landed; regloads(1) in flight
    asm volatile("s_waitcnt lgkmcnt(0)" ::: "memory");
    __builtin_amdgcn_s_barrier();
    readF(lds[0]);
    asm volatile("s_waitcnt lgkmcnt(0)" ::: "memory");
    __builtin_amdgcn_s_barrier();

    for (int t = 0; t < NT; ++t) {
        bf16_t* nxt = lds[(t & 1) ^ 1];
        const bool pf = (t + 1 < NT);

        // ---- overlapped region: staging for t+1 interleaves with MFMA(t) ----
        if (pf) {
            writeR(nxt);                      // rS(t+1) (only VM outstanding this old)
            stageG(nxt, (t + 1) << 5);
            if (t + 2 < NT) loadR((t + 2) << 5);
        }
#pragma unroll
        for (int j = 0; j < 4; ++j)
#pragma unroll
            for (int i = 0; i < 4; ++i) {
                acc[i][j] = MFMA16(aH[i], bH[j], acc[i][j]);
                if constexpr (SPL) {
                    acc[i][j] = MFMA16(aH[i], bL[j], acc[i][j]);
                    acc[i][j] = MFMA16(aL[i], bH[j], acc[i][j]);
                }
            }
        // ---- fence: tile t+1 fully in LDS ----
        if (pf && (t + 2 < NT))
            asm volatile("s_waitcnt vmcnt(4)" ::: "memory");   // gloads(t+1) landed
        else
            asm volatile("s_waitcnt vmcnt(0)" ::: "memory");
        asm volatile("s_waitcnt lgkmcnt(0)" ::: "memory");     // ds_writes landed
        __builtin_amdgcn_s_barrier();
        if (pf) {
            readF(nxt);
            asm volatile("s_waitcnt lgkmcnt(0)" ::: "memory"); // reads drained
        }
        __builtin_amdgcn_s_barrier();                          // safe to overwrite next iter
    }

    // epilogue (C/D layout: col = lane&15, row = (lane>>4)*4 + reg)
    const int frow = q * 4;
#pragma unroll
    for (int i = 0; i < 4; ++i) {
        const int rgl = row0 + wr + i * 16 + frow;
#pragma unroll
        for (int j = 0; j < 4; ++j) {
            const int cg = col0 + wc + j * 16 + fr;
            if constexpr (EPI == 0) {
                float* C = (float*)C0 + bz * sC;
#pragma unroll
                for (int r = 0; r < 4; ++r)
                    C[(long)(rgl + r) * N + cg] = acc[i][j][r];
            } else if constexpr (EPI == 1) {
                bf16_t* Ch = (bf16_t*)C0 + bz * sC;
                bf16_t* Cl = (bf16_t*)C1 + bz * sC;
#pragma unroll
                for (int r = 0; r < 4; ++r) {
                    float v = acc[i][j][r];
                    bf16_t h = (bf16_t)v;
                    Ch[(long)(rgl + r) * N + cg] = h;
                    Cl[(long)(rgl + r) * N + cg] = (bf16_t)(v - (float)h);
                }
            } else if constexpr (EPI == 2) {
                bf16_t* Ch = (bf16_t*)C0 + bz * sC;
#pragma unroll
                for (int r = 0; r < 4; ++r)
                    Ch[(long)(rgl + r) * N + cg] = (bf16_t)acc[i][j][r];
            } else {
                float* C = (float*)C0 + bz * sC;
                const float badd = bias[cg];
#pragma unroll
                for (int r = 0; r < 4; ++r)
                    C[(long)(rgl + r) * N + cg] = acc[i][j][r] + badd;
            }
        }
    }
}

// ---------------------------------------------------------------------------
// Row softmax over length-1024 rows, in place (f32).
__global__ __launch_bounds__(256)
void softmax_rows(float* __restrict__ S)
{
    const long row = (long)blockIdx.x * 4 + (threadIdx.x >> 6);
    const int lane = threadIdx.x & 63;
    float* p = S + row * (long)TENC;

    float4 v[4];
    float m = -INFINITY;
#pragma unroll
    for (int i = 0; i < 4; ++i) {
        v[i] = *(const float4*)&p[i * 256 + lane * 4];
        m = fmaxf(fmaxf(fmaxf(v[i].x, v[i].y), fmaxf(v[i].z, v[i].w)), m);
    }
#pragma unroll
    for (int o = 32; o; o >>= 1) m = fmaxf(m, __shfl_xor(m, o, 64));

    float s = 0.f;
#pragma unroll
    for (int i = 0; i < 4; ++i) {
        v[i].x = __expf(v[i].x - m);
        v[i].y = __expf(v[i].y - m);
        v[i].z = __expf(v[i].z - m);
        v[i].w = __expf(v[i].w - m);
        s += v[i].x + v[i].y + v[i].z + v[i].w;
    }
#pragma unroll
    for (int o = 32; o; o >>= 1) s += __shfl_xor(s, o, 64);

    const float inv = 1.0f / s;
#pragma unroll
    for (int i = 0; i < 4; ++i) {
        v[i].x *= inv; v[i].y *= inv; v[i].z *= inv; v[i].w *= inv;
        *(float4*)&p[i * 256 + lane * 4] = v[i];
    }
}

// ---------------------------------------------------------------------------
// fp32 fallback GEMM (safety net for tiny ws)
#define TILE_M 64
#define TILE_N 64
#define TILE_K 16
template<bool B_TRANS, bool ADD_BIAS>
__global__ __launch_bounds__(256)
void gemm_f32(const float* __restrict__ A, const float* __restrict__ Bm,
              const float* __restrict__ bias, float* __restrict__ C,
              int M, int N, int K, int lda, int ldb,
              long strideA, long strideB, long strideC)
{
    __shared__ float As[TILE_K][TILE_M + 4];
    __shared__ float Bs[TILE_K][TILE_N + 4];
    const int b = blockIdx.z;
    A += (long)b * strideA; Bm += (long)b * strideB; C += (long)b * strideC;
    const int tid = threadIdx.x;
    const int tx = tid & 15, ty = tid >> 4;
    const int row0 = blockIdx.y * TILE_M, col0 = blockIdx.x * TILE_N;
    const int am = tid >> 2, ak = (tid & 3) * 4;
    float acc[4][4] = {};
    for (int kt = 0; kt < K; kt += TILE_K) {
        float4 a4 = *(const float4*)&A[(long)(row0 + am) * lda + kt + ak];
        float4 b4;
        if (B_TRANS) b4 = *(const float4*)&Bm[(long)(col0 + am) * ldb + kt + ak];
        else {
            const int bk_ = tid >> 4, bn = (tid & 15) * 4;
            b4 = *(const float4*)&Bm[(long)(kt + bk_) * ldb + col0 + bn];
        }
        __syncthreads();
        As[ak + 0][am] = a4.x; As[ak + 1][am] = a4.y;
        As[ak + 2][am] = a4.z; As[ak + 3][am] = a4.w;
        if (B_TRANS) {
            Bs[ak + 0][am] = b4.x; Bs[ak + 1][am] = b4.y;
            Bs[ak + 2][am] = b4.z; Bs[ak + 3][am] = b4.w;
        } else {
            const int bk_ = tid >> 4, bn = (tid & 15) * 4;
            *(float4*)&Bs[bk_][bn] = b4;
        }
        __syncthreads();
#pragma unroll
        for (int k = 0; k < TILE_K; ++k) {
            float4 av = *(const float4*)&As[k][ty * 4];
            float4 bv4 = *(const float4*)&Bs[k][tx * 4];
            float ar[4] = {av.x, av.y, av.z, av.w};
            float br[4] = {bv4.x, bv4.y, bv4.z, bv4.w};
#pragma unroll
            for (int i = 0; i < 4; ++i)
#pragma unroll
                for (int j = 0; j < 4; ++j)
                    acc[i][j] = fmaf(ar[i], br[j], acc[i][j]);
        }
    }
    float4 bias4 = make_float4(0.f, 0.f, 0.f, 0.f);
    if (ADD_BIAS) bias4 = *(const float4*)&bias[col0 + tx * 4];
#pragma unroll
    for (int i = 0; i < 4; ++i) {
        float4 o;
        o.x = acc[i][0] + bias4.x; o.y = acc[i][1] + bias4.y;
        o.z = acc[i][2] + bias4.z; o.w = acc[i][3] + bias4.w;
        *(float4*)&C[(long)(row0 + ty * 4 + i) * N + col0 + tx * 4] = o;
    }
}

// ---------------------------------------------------------------------------
extern "C" void kernel_launch(void* const* d_in, const int* in_sizes, int n_in,
                              void* d_out, int out_size, void* d_ws, size_t ws_size,
                              hipStream_t stream)
{
    const float* enc = (const float*)d_in[0];   // [32,1024,512]
    const float* dec = (const float*)d_in[1];   // [32,512,512]
    const float* Wk  = (const float*)d_in[2];   // [512,512]
    const float* Wv  = (const float*)d_in[4];   // [512,512]
    const float* bv  = (const float*)d_in[5];   // [512]

    const long nD = (long)BB * TDEC * NST;      // 8388608
    const long nW = (long)DDIM * NST;           // 262144

    float* ctx   = (float*)d_out;               // [32,512,512]
    float* attnF = ctx + nD;                    // [32,512,1024]

    const size_t need = 35127296;
    const dim3 blk(256);

    if (ws_size < need) {
        float* ws = (float*)d_ws;
        gemm_f32<true, false><<<dim3(DDIM / 64, (BB * TDEC) / 64, 1), blk, 0, stream>>>(
            dec, Wk, nullptr, ws, BB * TDEC, DDIM, NST, NST, NST, 0, 0, 0);
        gemm_f32<true, false><<<dim3(TENC / 64, TDEC / 64, BB), blk, 0, stream>>>(
            ws, enc, nullptr, attnF, TDEC, TENC, DDIM, DDIM, DDIM,
            (long)TDEC * DDIM, (long)TENC * DDIM, (long)TDEC * TENC);
        softmax_rows<<<(BB * TDEC) / 4, blk, 0, stream>>>(attnF);
        gemm_f32<false, false><<<dim3(DDIM / 64, TDEC / 64, BB), blk, 0, stream>>>(
            attnF, enc, nullptr, ws, TDEC, DDIM, TENC, TENC, DDIM,
            (long)TDEC * TENC, (long)TENC * DDIM, (long)TDEC * DDIM);
        gemm_f32<false, true><<<dim3(NST / 64, (BB * TDEC) / 64, 1), blk, 0, stream>>>(
            ws, Wv, bv, ctx, BB * TDEC, NST, DDIM, DDIM, NST, 0, 0, 0);
        return;
    }

    // ws layout (bytes)
    char* w = (char*)d_ws;
    bf16_t* EVT  = (bf16_t*)(w);                 // [32][512][1024] bf16 = 33.55MB
    bf16_t* Wkhi = (bf16_t*)(w + 33554432);
    bf16_t* Wklo = (bf16_t*)(w + 34078720);
    bf16_t* WvT  = (bf16_t*)(w + 34603008);

    // DK split lives in the not-yet-written ctx output region (exactly 33.55MB)
    bf16_t* DKhi = (bf16_t*)ctx;
    bf16_t* DKlo = DKhi + nD;

    // 1) tiny weight preps
    split_f32_bf16<<<(unsigned)(nW / 4 / 256), blk, 0, stream>>>(Wk, Wkhi, Wklo, nW / 4);
    transpose_to_bf16<<<dim3(NST / 64, DDIM / 64, 1), blk, 0, stream>>>(Wv, WvT, DDIM, NST);

    // 2) DK = dec @ Wk^T  (A: dec f32 reg-split; B: Wk split gload) -> split bf16
    gemm_u<3, 1, 1><<<dim3(DDIM / 128, (BB * TDEC) / 128, 1), blk, 0, stream>>>(
        dec, nullptr, nullptr, nullptr, Wkhi, Wklo, nullptr, DKhi, DKlo,
        BB * TDEC, DDIM, NST, 0, 0, 0, 0, 0);

    // 3) score = DK @ enc^T  (A: DK split gload; B: enc f32 reg-split) -> f32 attn
    gemm_u<1, 3, 0><<<dim3(TENC / 128, TDEC / 128, BB), blk, 0, stream>>>(
        nullptr, DKhi, DKlo, enc, nullptr, nullptr, nullptr, attnF, nullptr,
        TDEC, TENC, DDIM,
        0, (long)TDEC * DDIM, (long)TENC * DDIM, 0, (long)TDEC * TENC);

    // 4) EV^T = Wv^T @ enc^T  (A: WvT bf16 gload; B: enc f32 reg-bf16) -> bf16 ws
    gemm_u<0, 2, 2><<<dim3(TENC / 128, NST / 128, BB), blk, 0, stream>>>(
        nullptr, WvT, nullptr, enc, nullptr, nullptr, nullptr, EVT, nullptr,
        NST, TENC, DDIM,
        0, 0, (long)TENC * DDIM, 0, (long)NST * TENC);

    // 5) softmax rows, in place f32
    softmax_rows<<<(BB * TDEC) / 4, blk, 0, stream>>>(attnF);

    // 6) ctx = attn @ EV + bv  (A: attn f32 reg-bf16; B: EVT gload) -> f32 ctx
    //    (overwrites the DK scratch — DK dead after step 3)
    gemm_u<2, 0, 3><<<dim3(NST / 128, TDEC / 128, BB), blk, 0, stream>>>(
        attnF, nullptr, nullptr, nullptr, EVT, nullptr, bv, ctx, nullptr,
        TDEC, NST, TENC,
        (long)TDEC * TENC, 0, 0, (long)NST * TENC, (long)TDEC * NST);
}

// Round 10
// 157.460 us; speedup vs baseline: 1.6303x; 1.2034x over previous
//
#include <hip/hip_runtime.h>
#include <math.h>

#define BB    32
#define TENC  1024
#define TDEC  512
#define DDIM  512
#define NST   512

typedef _Float16 f16_t;
typedef _Float16 f16x8 __attribute__((ext_vector_type(8)));
typedef _Float16 f16x4 __attribute__((ext_vector_type(4)));
typedef float    f32x4 __attribute__((ext_vector_type(4)));

#define GLOAD_LDS16(gp, lp) __builtin_amdgcn_global_load_lds( \
    (const __attribute__((address_space(1))) unsigned int*)(const void*)(gp), \
    (__attribute__((address_space(3))) unsigned int*)(lp), 16, 0, 0)

static __device__ __forceinline__ f32x4 MFMA16H(f16x8 a, f16x8 b, f32x4 c) {
    return __builtin_amdgcn_mfma_f32_16x16x32_f16(a, b, c, 0, 0, 0);
}

// ---------------------------------------------------------------------------
// f32 -> f16 cast, 8 elems/thread
__global__ __launch_bounds__(256)
void cvt_f32_f16(const float* __restrict__ x, f16_t* __restrict__ y, long n8)
{
    long i = (long)blockIdx.x * 256 + threadIdx.x;
    if (i >= n8) return;
    float4 a = *(const float4*)&x[i * 8];
    float4 b = *(const float4*)&x[i * 8 + 4];
    f16x8 o;
    o[0] = (f16_t)a.x; o[1] = (f16_t)a.y; o[2] = (f16_t)a.z; o[3] = (f16_t)a.w;
    o[4] = (f16_t)b.x; o[5] = (f16_t)b.y; o[6] = (f16_t)b.z; o[7] = (f16_t)b.w;
    *(f16x8*)&y[i * 8] = o;
}

// ---------------------------------------------------------------------------
// Tiled transpose f32 -> f16 (Wv only)
__global__ __launch_bounds__(256)
void transpose_to_f16(const float* __restrict__ in, f16_t* __restrict__ out,
                      int R, int C)
{
    __shared__ f16_t tile[64][65];
    const int c0 = blockIdx.x * 64, r0 = blockIdx.y * 64;
    const int t = threadIdx.x;
    const int rr = t >> 4;
    const int cc = (t & 15) * 4;
#pragma unroll
    for (int p = 0; p < 4; ++p) {
        int r = rr + p * 16;
        float4 v = *(const float4*)&in[(long)(r0 + r) * C + c0 + cc];
        tile[r][cc + 0] = (f16_t)v.x;
        tile[r][cc + 1] = (f16_t)v.y;
        tile[r][cc + 2] = (f16_t)v.z;
        tile[r][cc + 3] = (f16_t)v.w;
    }
    __syncthreads();
    const int dr = t >> 2;
    const int tc = (t & 3) * 16;
    f16_t tmp[16];
#pragma unroll
    for (int e = 0; e < 16; ++e) tmp[e] = tile[tc + e][dr];
    *(f16x8*)&out[(long)(c0 + dr) * R + r0 + tc]     = *(f16x8*)&tmp[0];
    *(f16x8*)&out[(long)(c0 + dr) * R + r0 + tc + 8] = *(f16x8*)&tmp[8];
}

// ---------------------------------------------------------------------------
// Plain-f16 MFMA GEMM: C[M,N] = A[M,K] @ B'[N,K]^T (+bias).
// Both operands K-contiguous f16, staged via global_load_lds (2 issues each/tile).
// BM=BN=128, BK=32, 4 waves (2x2 wave-tile 64x64), double-buffered swizzled LDS
// (32KB total -> ~5 blocks/CU). R4-proven barrier skeleton + counted vmcnt(4).
// EPI: 0 = f32 out, 2 = f16 out, 3 = f32 + bias.
template<int EPI>
__global__ __launch_bounds__(256)
void gemm_h(const f16_t* __restrict__ A, const f16_t* __restrict__ B,
            const float* __restrict__ bias, void* __restrict__ C0,
            int M, int N, int K, long sA, long sB, long sC)
{
    __shared__ f16_t lds[2][8192];   // per buf: A [0,4096), B [4096,8192)

    const int tid  = threadIdx.x;
    const int wave = tid >> 6;
    const int lane = tid & 63;

    // T1: bijective XCD swizzle (all grids are multiples of 8)
    const int gx = gridDim.x, gy = gridDim.y;
    const long nwg = (long)gx * gy * gridDim.z;
    const long fo  = ((long)blockIdx.z * gy + blockIdx.y) * gx + blockIdx.x;
    const long f2 = (fo & 7) * (nwg >> 3) + (fo >> 3);
    const int bx  = (int)(f2 % gx);
    const int by  = (int)((f2 / gx) % gy);
    const long bz = f2 / ((long)gx * gy);

    const f16_t* Ab = A + bz * sA;
    const f16_t* Bb = B + bz * sB;

    const int row0 = by * 128;
    const int col0 = bx * 128;

    // staging: per issue 256 thr x 16B = 64 rows x 32 f16. LDS dest linear;
    // global k-slot pre-swizzled (both-sides-or-neither rule).
    const int srow  = wave * 16 + (lane >> 2);           // 0..63
    const int sslot = (lane & 3) ^ ((srow >> 1) & 3);
    const int wdst  = wave * 512;
    const long aOff0 = (long)(row0 + srow) * K + sslot * 8;
    const long aOff1 = (long)(row0 + 64 + srow) * K + sslot * 8;
    const long bOff0 = (long)(col0 + srow) * K + sslot * 8;
    const long bOff1 = (long)(col0 + 64 + srow) * K + sslot * 8;

    // fragment read offsets (swizzle-matched), wave-tile 64x64 at (wr,wc)
    const int fr = lane & 15;
    const int q  = lane >> 4;
    const int wr = (wave >> 1) * 64;
    const int wc = (wave & 1) * 64;
    int aro[4], bro[4];
#pragma unroll
    for (int i = 0; i < 4; ++i) {
        const int r = wr + i * 16 + fr;
        aro[i] = r * 32 + ((q ^ ((r >> 1) & 3)) * 8);
    }
#pragma unroll
    for (int j = 0; j < 4; ++j) {
        const int r = wc + j * 16 + fr;
        bro[j] = r * 32 + ((q ^ ((r >> 1) & 3)) * 8);
    }

    f32x4 acc[4][4] = {};
    const int NT = K >> 5;

#define STAGE(buf, kt) do {                                   \
        GLOAD_LDS16(Ab + aOff0 + (kt), &(buf)[wdst]);         \
        GLOAD_LDS16(Ab + aOff1 + (kt), &(buf)[2048 + wdst]);  \
        GLOAD_LDS16(Bb + bOff0 + (kt), &(buf)[4096 + wdst]);  \
        GLOAD_LDS16(Bb + bOff1 + (kt), &(buf)[6144 + wdst]);  \
    } while (0)

    STAGE(lds[0], 0);

    for (int t = 0; t < NT; ++t) {
        const f16_t* cur = lds[t & 1];
        f16_t* nxt = lds[(t & 1) ^ 1];
        const bool pf = (t + 1 < NT);

        __builtin_amdgcn_sched_barrier(0);
        __builtin_amdgcn_s_barrier();      // all waves done reading nxt's old data
        if (pf) {
            STAGE(nxt, (t + 1) << 5);
            asm volatile("s_waitcnt vmcnt(4)" ::: "memory");  // tile t landed
        } else {
            asm volatile("s_waitcnt vmcnt(0)" ::: "memory");
        }
        __builtin_amdgcn_s_barrier();      // tile t visible to all waves
        __builtin_amdgcn_sched_barrier(0);

        f16x8 aH[4], bH[4];
#pragma unroll
        for (int i = 0; i < 4; ++i) aH[i] = *(const f16x8*)&cur[aro[i]];
#pragma unroll
        for (int j = 0; j < 4; ++j) bH[j] = *(const f16x8*)&cur[4096 + bro[j]];

#pragma unroll
        for (int j = 0; j < 4; ++j)
#pragma unroll
            for (int i = 0; i < 4; ++i)
                acc[i][j] = MFMA16H(aH[i], bH[j], acc[i][j]);
    }
#undef STAGE

    // epilogue (C/D layout: col = lane&15, row = (lane>>4)*4 + reg)
    const int frow = q * 4;
#pragma unroll
    for (int i = 0; i < 4; ++i) {
        const int rgl = row0 + wr + i * 16 + frow;
#pragma unroll
        for (int j = 0; j < 4; ++j) {
            const int cg = col0 + wc + j * 16 + fr;
            if constexpr (EPI == 0) {
                float* C = (float*)C0 + bz * sC;
#pragma unroll
                for (int r = 0; r < 4; ++r)
                    C[(long)(rgl + r) * N + cg] = acc[i][j][r];
            } else if constexpr (EPI == 2) {
                f16_t* C = (f16_t*)C0 + bz * sC;
#pragma unroll
                for (int r = 0; r < 4; ++r)
                    C[(long)(rgl + r) * N + cg] = (f16_t)acc[i][j][r];
            } else {
                float* C = (float*)C0 + bz * sC;
                const float badd = bias[cg];
#pragma unroll
                for (int r = 0; r < 4; ++r)
                    C[(long)(rgl + r) * N + cg] = acc[i][j][r] + badd;
            }
        }
    }
}

// ---------------------------------------------------------------------------
// Row softmax over length-1024 rows, in place (f32) + f16 copy.
__global__ __launch_bounds__(256)
void softmax_rows(float* __restrict__ S, f16_t* __restrict__ Sh)
{
    const long row = (long)blockIdx.x * 4 + (threadIdx.x >> 6);
    const int lane = threadIdx.x & 63;
    float* p = S + row * (long)TENC;

    float4 v[4];
    float m = -INFINITY;
#pragma unroll
    for (int i = 0; i < 4; ++i) {
        v[i] = *(const float4*)&p[i * 256 + lane * 4];
        m = fmaxf(fmaxf(fmaxf(v[i].x, v[i].y), fmaxf(v[i].z, v[i].w)), m);
    }
#pragma unroll
    for (int o = 32; o; o >>= 1) m = fmaxf(m, __shfl_xor(m, o, 64));

    float s = 0.f;
#pragma unroll
    for (int i = 0; i < 4; ++i) {
        v[i].x = __expf(v[i].x - m);
        v[i].y = __expf(v[i].y - m);
        v[i].z = __expf(v[i].z - m);
        v[i].w = __expf(v[i].w - m);
        s += v[i].x + v[i].y + v[i].z + v[i].w;
    }
#pragma unroll
    for (int o = 32; o; o >>= 1) s += __shfl_xor(s, o, 64);

    const float inv = 1.0f / s;
#pragma unroll
    for (int i = 0; i < 4; ++i) {
        v[i].x *= inv; v[i].y *= inv; v[i].z *= inv; v[i].w *= inv;
        *(float4*)&p[i * 256 + lane * 4] = v[i];
        if (Sh) {
            f16x4 h;
            h[0] = (f16_t)v[i].x; h[1] = (f16_t)v[i].y;
            h[2] = (f16_t)v[i].z; h[3] = (f16_t)v[i].w;
            *(f16x4*)&Sh[row * (long)TENC + i * 256 + lane * 4] = h;
        }
    }
}

// ---------------------------------------------------------------------------
// fp32 fallback GEMM (safety net for tiny ws)
#define TILE_M 64
#define TILE_N 64
#define TILE_K 16
template<bool B_TRANS, bool ADD_BIAS>
__global__ __launch_bounds__(256)
void gemm_f32(const float* __restrict__ A, const float* __restrict__ Bm,
              const float* __restrict__ bias, float* __restrict__ C,
              int M, int N, int K, int lda, int ldb,
              long strideA, long strideB, long strideC)
{
    __shared__ float As[TILE_K][TILE_M + 4];
    __shared__ float Bs[TILE_K][TILE_N + 4];
    const int b = blockIdx.z;
    A += (long)b * strideA; Bm += (long)b * strideB; C += (long)b * strideC;
    const int tid = threadIdx.x;
    const int tx = tid & 15, ty = tid >> 4;
    const int row0 = blockIdx.y * TILE_M, col0 = blockIdx.x * TILE_N;
    const int am = tid >> 2, ak = (tid & 3) * 4;
    float acc[4][4] = {};
    for (int kt = 0; kt < K; kt += TILE_K) {
        float4 a4 = *(const float4*)&A[(long)(row0 + am) * lda + kt + ak];
        float4 b4;
        if (B_TRANS) b4 = *(const float4*)&Bm[(long)(col0 + am) * ldb + kt + ak];
        else {
            const int bk_ = tid >> 4, bn = (tid & 15) * 4;
            b4 = *(const float4*)&Bm[(long)(kt + bk_) * ldb + col0 + bn];
        }
        __syncthreads();
        As[ak + 0][am] = a4.x; As[ak + 1][am] = a4.y;
        As[ak + 2][am] = a4.z; As[ak + 3][am] = a4.w;
        if (B_TRANS) {
            Bs[ak + 0][am] = b4.x; Bs[ak + 1][am] = b4.y;
            Bs[ak + 2][am] = b4.z; Bs[ak + 3][am] = b4.w;
        } else {
            const int bk_ = tid >> 4, bn = (tid & 15) * 4;
            *(float4*)&Bs[bk_][bn] = b4;
        }
        __syncthreads();
#pragma unroll
        for (int k = 0; k < TILE_K; ++k) {
            float4 av = *(const float4*)&As[k][ty * 4];
            float4 bv4 = *(const float4*)&Bs[k][tx * 4];
            float ar[4] = {av.x, av.y, av.z, av.w};
            float br[4] = {bv4.x, bv4.y, bv4.z, bv4.w};
#pragma unroll
            for (int i = 0; i < 4; ++i)
#pragma unroll
                for (int j = 0; j < 4; ++j)
                    acc[i][j] = fmaf(ar[i], br[j], acc[i][j]);
        }
    }
    float4 bias4 = make_float4(0.f, 0.f, 0.f, 0.f);
    if (ADD_BIAS) bias4 = *(const float4*)&bias[col0 + tx * 4];
#pragma unroll
    for (int i = 0; i < 4; ++i) {
        float4 o;
        o.x = acc[i][0] + bias4.x; o.y = acc[i][1] + bias4.y;
        o.z = acc[i][2] + bias4.z; o.w = acc[i][3] + bias4.w;
        *(float4*)&C[(long)(row0 + ty * 4 + i) * N + col0 + tx * 4] = o;
    }
}

// ---------------------------------------------------------------------------
extern "C" void kernel_launch(void* const* d_in, const int* in_sizes, int n_in,
                              void* d_out, int out_size, void* d_ws, size_t ws_size,
                              hipStream_t stream)
{
    const float* enc = (const float*)d_in[0];   // [32,1024,512]
    const float* dec = (const float*)d_in[1];   // [32,512,512]
    const float* Wk  = (const float*)d_in[2];   // [512,512] rows d, cols n
    const float* Wv  = (const float*)d_in[4];   // [512,512]
    const float* bv  = (const float*)d_in[5];   // [512]

    const long nE = (long)BB * TENC * DDIM;     // 16777216
    const long nD = (long)BB * TDEC * NST;      // 8388608
    const long nW = (long)DDIM * NST;           // 262144

    float* ctx   = (float*)d_out;               // [32,512,512]
    float* attnF = ctx + nD;                    // [32,512,1024]

    const size_t need = 68157440;
    const dim3 blk(256);

    if (ws_size < need) {
        float* ws = (float*)d_ws;
        gemm_f32<true, false><<<dim3(DDIM / 64, (BB * TDEC) / 64, 1), blk, 0, stream>>>(
            dec, Wk, nullptr, ws, BB * TDEC, DDIM, NST, NST, NST, 0, 0, 0);
        gemm_f32<true, false><<<dim3(TENC / 64, TDEC / 64, BB), blk, 0, stream>>>(
            ws, enc, nullptr, attnF, TDEC, TENC, DDIM, DDIM, DDIM,
            (long)TDEC * DDIM, (long)TENC * DDIM, (long)TDEC * TENC);
        softmax_rows<<<(BB * TDEC) / 4, blk, 0, stream>>>(attnF, nullptr);
        gemm_f32<false, false><<<dim3(DDIM / 64, TDEC / 64, BB), blk, 0, stream>>>(
            attnF, enc, nullptr, ws, TDEC, DDIM, TENC, TENC, DDIM,
            (long)TDEC * TENC, (long)TENC * DDIM, (long)TDEC * DDIM);
        gemm_f32<false, true><<<dim3(NST / 64, (BB * TDEC) / 64, 1), blk, 0, stream>>>(
            ws, Wv, bv, ctx, BB * TDEC, NST, DDIM, DDIM, NST, 0, 0, 0);
        return;
    }

    // ws layout (bytes):
    //   [0,        33.55MB) EVT  f16 [32][512 v][1024 te]
    //   [33.55MB,  67.11MB) Ef16 f16 [32][1024][512]   -> attnB f16 after use
    //   [67.11MB,  +0.5MB)  Wk16
    //   [67.63MB,  +0.5MB)  WvT16
    char* w = (char*)d_ws;
    f16_t* EVT   = (f16_t*)(w);
    f16_t* Ef16  = (f16_t*)(w + 33554432);
    f16_t* Wk16  = (f16_t*)(w + 67108864);
    f16_t* WvT16 = (f16_t*)(w + 67633152);
    f16_t* attnB = Ef16;                        // alias, live after EVT+score

    // dec16/DK16 in the not-yet-written ctx output region (16.8MB each)
    f16_t* dec16 = (f16_t*)ctx;
    f16_t* DK16  = dec16 + nD;

    // 1) conversions
    cvt_f32_f16<<<(unsigned)(nE / 8 / 256), blk, 0, stream>>>(enc, Ef16, nE / 8);
    cvt_f32_f16<<<(unsigned)(nD / 8 / 256), blk, 0, stream>>>(dec, dec16, nD / 8);
    cvt_f32_f16<<<(unsigned)(nW / 8 / 256), blk, 0, stream>>>(Wk, Wk16, nW / 8);
    transpose_to_f16<<<dim3(NST / 64, DDIM / 64, 1), blk, 0, stream>>>(Wv, WvT16, DDIM, NST);

    // 2) DK = dec @ Wk^T  -> f16 (DK[q,d] = sum_n dec[q,n] * Wk[d,n])
    gemm_h<2><<<dim3(DDIM / 128, (BB * TDEC) / 128, 1), blk, 0, stream>>>(
        dec16, Wk16, nullptr, DK16,
        BB * TDEC, DDIM, NST, 0, 0, 0);

    // 3) score = DK @ enc^T -> f32 attn region
    gemm_h<0><<<dim3(TENC / 128, TDEC / 128, BB), blk, 0, stream>>>(
        DK16, Ef16, nullptr, attnF,
        TDEC, TENC, DDIM,
        (long)TDEC * DDIM, (long)TENC * DDIM, (long)TDEC * TENC);

    // 4) EVT[v,te] = sum_d Wv[d,v] * enc[te,d]  -> f16 (EV^T)
    gemm_h<2><<<dim3(TENC / 128, NST / 128, BB), blk, 0, stream>>>(
        WvT16, Ef16, nullptr, EVT,
        NST, TENC, DDIM,
        0, (long)TENC * DDIM, (long)NST * TENC);

    // 5) softmax in place (f32) + f16 copy over the dead Ef16 region
    softmax_rows<<<(BB * TDEC) / 4, blk, 0, stream>>>(attnF, attnB);

    // 6) ctx = attn @ EV + bv  (A=attnB te-contig, B=EVT te-contig) -> f32
    gemm_h<3><<<dim3(NST / 128, TDEC / 128, BB), blk, 0, stream>>>(
        attnB, EVT, bv, ctx,
        TDEC, NST, TENC,
        (long)TDEC * TENC, (long)NST * TENC, (long)TDEC * NST);
}